// Round 8
// baseline (233.692 us; speedup 1.0000x reference)
//
#include <hip/hip_runtime.h>

#define DEV static __device__ __forceinline__

typedef __bf16 bf16x8 __attribute__((ext_vector_type(8)));
typedef float  f32x16 __attribute__((ext_vector_type(16)));

// 32x32 MFMA C/D row for reg r, lane-half hi (verified m74/m101)
DEV int rowmap(int r, int hi) { return (r & 3) + 8 * (r >> 2) + 4 * hi; }

// 256B-row bf16 tiles: 16B-block XOR4 swizzle (full bank spread)
DEV int swzQ(int row, int col) {
  return row * 256 + (((((col >> 3) ^ (row & 15)) << 3) | (col & 7)) << 1);
}

DEV unsigned pack2(float lo, float hi) {
  union { __bf16 h[2]; unsigned u; } x;
  x.h[0] = (__bf16)lo; x.h[1] = (__bf16)hi;
  return x.u;
}

// D-layout 16-row slab -> A/B fragment; half-swap via shfl_xor(.,32)+select.
DEV bf16x8 mk_frag(float d0, float d1, float d2, float d3,
                   float d4, float d5, float d6, float d7, int lane) {
  unsigned a0 = pack2(d0, d1), a1 = pack2(d2, d3);
  unsigned b0 = pack2(d4, d5), b1 = pack2(d6, d7);
  unsigned a0s = __shfl_xor(a0, 32), a1s = __shfl_xor(a1, 32);
  unsigned b0s = __shfl_xor(b0, 32), b1s = __shfl_xor(b1, 32);
  bool lo = lane < 32;
  union { unsigned u[4]; bf16x8 v; } r;
  r.u[0] = lo ? a0  : b0s;
  r.u[1] = lo ? a1  : b1s;
  r.u[2] = lo ? a0s : b0;
  r.u[3] = lo ? a1s : b1;
  return r.v;
}

DEV f32x16 fzero() {
  f32x16 z;
  #pragma unroll
  for (int i = 0; i < 16; ++i) z[i] = 0.f;
  return z;
}

// async global->LDS, 16B/lane, wave-uniform LDS base (m97 pattern)
DEV void gld16(const char* g, char* l) {
  __builtin_amdgcn_global_load_lds(
      (const __attribute__((address_space(1))) void*)g,
      (__attribute__((address_space(3))) void*)l, 16, 0, 0);
}

// Write S^T half-tile [128 e][128 kloc] from row-fragments.
// Lane (ml,hi) holds row k=colbase+ml, elements e=16kk+8hi+i. Pair lanes
// (ml, ml^1) via shfl to form u32 (k_even, k_odd) words; even lanes cover
// e<64 (kk 0..3), odd lanes e>=64 (kk 4..7).
DEV void st_write(char* SB, int colbase, const bf16x8 sf[8], int ml, int hi) {
  #pragma unroll
  for (int kk = 0; kk < 8; ++kk) {
    union { bf16x8 v; unsigned u[4]; } o, q;
    o.v = sf[kk];
    #pragma unroll
    for (int x = 0; x < 4; ++x) q.u[x] = __shfl_xor(o.u[x], 1);
    bool even = ((ml & 1) == 0);
    if (even ? (kk < 4) : (kk >= 4)) {
      int col = colbase + (ml & ~1);
      #pragma unroll
      for (int i = 0; i < 8; ++i) {
        int e = 16 * kk + 8 * hi + i;
        union { __bf16 h[2]; unsigned u; } pk;
        pk.h[0] = even ? o.v[i] : q.v[i];
        pk.h[1] = even ? q.v[i] : o.v[i];
        *reinterpret_cast<unsigned*>(SB + swzQ(e, col)) = pk.u;
      }
    }
  }
}

// prep: M[a,b] = sum_d Xrow(a,d) * Y[b,d]; Xrow = transx ? X[d][a] : X[a][d].
// mode G : X=Wq, Y=Wk, transx=0 -> M1[e,e'] = (Wq Wk^T)[e,e']
// mode H': X=Wo, Y=Wv, transx=1 -> M3[eo,e] = sum_d Wv[e,d] Wo[d,eo] = H^T
__global__ void prep_mat(const float* __restrict__ X, const float* __restrict__ Y,
                         char* __restrict__ dst, int transx) {
  extern __shared__ char pm[];
  float* yl = reinterpret_cast<float*>(pm);          // [128][129]
  float* xl = yl + 128 * 129;                        // [16][129]
  int t = threadIdx.x;                               // 256 threads
  int a0 = blockIdx.x * 16;
  for (int i = t; i < 16384; i += 256) yl[(i >> 7) * 129 + (i & 127)] = Y[i];
  for (int i = t; i < 2048; i += 256) {
    int aa = i >> 7, d = i & 127;
    xl[aa * 129 + d] = transx ? X[d * 128 + a0 + aa] : X[(a0 + aa) * 128 + d];
  }
  __syncthreads();
  int b = t & 127, ah = t >> 7;
  #pragma unroll
  for (int aa = 0; aa < 8; ++aa) {
    int a = ah * 8 + aa;
    float acc = 0.f;
    for (int d = 0; d < 128; ++d) acc += xl[a * 129 + d] * yl[b * 129 + d];
    *reinterpret_cast<__bf16*>(dst + swzQ(a0 + a, b)) = (__bf16)acc;
  }
}

// prep: v1[e]=Wq[e,:].bk, v2[e]=Wk[e,:].bq, w2[e]=bv.Wo[:,e], cst=bq.bk
__global__ void prep_v(const float* __restrict__ Wq, const float* __restrict__ Wk,
                       const float* __restrict__ Wo,
                       const float* __restrict__ bq, const float* __restrict__ bk,
                       const float* __restrict__ bv, float* __restrict__ dstf) {
  int e = threadIdx.x;  // 128
  float a1 = 0.f, a2 = 0.f, a3 = 0.f;
  for (int d = 0; d < 128; ++d) {
    a1 += Wq[e * 128 + d] * bk[d];
    a2 += Wk[e * 128 + d] * bq[d];
    a3 += bv[d] * Wo[d * 128 + e];
  }
  dstf[e] = a1; dstf[128 + e] = a2; dstf[256 + e] = a3;
  if (e == 0) {
    float c = 0.f;
    for (int d = 0; d < 128; ++d) c += bq[d] * bk[d];
    dstf[384] = c;
  }
}

// Main: scores = S G S^T + a + c + cst (relu, scale), U = P S, out = U H + rs w2 + bo.
// LDS: SA 32K (G -> Sr-half -> H^T), SB 32K (S^T-half), spare 2K (a[256], rs[256]).
// 66K LDS -> 2 blocks/CU, 16 waves/CU = 4/SIMD; 512-thr blocks -> VGPR ~128 (proven).
__global__ __launch_bounds__(512, 2)
void sapd_fused(const float* __restrict__ S,
                const float* __restrict__ bo,
                const float* __restrict__ lg, const float* __restrict__ lb,
                const char* __restrict__ ws,
                float* __restrict__ out)
{
  extern __shared__ char smem[];
  char* SA = smem;
  char* SB = smem + 32768;
  float* a_lds  = reinterpret_cast<float*>(smem + 65536);  // [256]
  float* rs_lds = a_lds + 256;                             // [256]

  const int tid  = threadIdx.x;
  const int lane = tid & 63;
  const int w    = tid >> 6;    // wave 0..7 owns j rows [32w, 32w+32)
  const int ml   = lane & 31;
  const int hi   = lane >> 5;
  const size_t sbase = (size_t)blockIdx.x * (256 * 128);
  const float* wsf = reinterpret_cast<const float*>(ws + 65536);

  // ---- DMA G -> SA (32 x 1KB chunks) ----
  #pragma unroll
  for (int j = 0; j < 4; ++j) {
    int c = w + 8 * j;
    gld16(ws + c * 1024 + lane * 16, SA + c * 1024);
  }

  // ---- S row-fragments (own 32 rows) ----
  bf16x8 sfrag[8];
  {
    const float* srow = S + sbase + (size_t)(32 * w + ml) * 128;
    #pragma unroll
    for (int kk = 0; kk < 8; ++kk) {
      float4 a = *reinterpret_cast<const float4*>(srow + 16 * kk + 8 * hi);
      float4 b = *reinterpret_cast<const float4*>(srow + 16 * kk + 8 * hi + 4);
      bf16x8 f;
      f[0] = (__bf16)a.x; f[1] = (__bf16)a.y; f[2] = (__bf16)a.z; f[3] = (__bf16)a.w;
      f[4] = (__bf16)b.x; f[5] = (__bf16)b.y; f[6] = (__bf16)b.z; f[7] = (__bf16)b.w;
      sfrag[kk] = f;
    }
  }

  // ---- S^T half0 (kappa 0..127) from waves 0-3 ----
  if (w < 4) st_write(SB, 32 * w, sfrag, ml, hi);
  __syncthreads();  // #1: G staged

  // ---- R-proj SWAPPED: racc[e][j] = sum_e' G[e,e'] S[j,e'] -> rfrag regs ----
  bf16x8 rfrag[8];
  {
    f32x16 racc[4];
    #pragma unroll
    for (int t = 0; t < 4; ++t) racc[t] = fzero();
    #pragma unroll
    for (int kk = 0; kk < 8; ++kk) {
      #pragma unroll
      for (int t = 0; t < 4; ++t) {
        bf16x8 gf = *reinterpret_cast<const bf16x8*>(
            SA + swzQ(32 * t + ml, 16 * kk + 8 * hi));
        racc[t] = __builtin_amdgcn_mfma_f32_32x32x16_bf16(gf, sfrag[kk], racc[t], 0, 0, 0);
      }
    }
    #pragma unroll
    for (int t = 0; t < 4; ++t) {
      rfrag[2 * t]     = mk_frag(racc[t][0], racc[t][1], racc[t][2], racc[t][3],
                                 racc[t][4], racc[t][5], racc[t][6], racc[t][7], lane);
      rfrag[2 * t + 1] = mk_frag(racc[t][8], racc[t][9], racc[t][10], racc[t][11],
                                 racc[t][12], racc[t][13], racc[t][14], racc[t][15], lane);
    }
  }

  // ---- bias MFMA: row0 = c[j] = S.v2, row1 = a[j] = S.v1 ----
  float c_own;
  {
    f32x16 sa2 = fzero();
    #pragma unroll
    for (int kk = 0; kk < 8; ++kk) {
      bf16x8 vmf;
      if (ml < 2) {
        const float* vp = wsf + (ml == 0 ? 128 : 0);  // row0=v2(c), row1=v1(a)
        #pragma unroll
        for (int i = 0; i < 8; ++i) vmf[i] = (__bf16)vp[16 * kk + 8 * hi + i];
      } else {
        #pragma unroll
        for (int i = 0; i < 8; ++i) vmf[i] = (__bf16)0.f;
      }
      sa2 = __builtin_amdgcn_mfma_f32_32x32x16_bf16(vmf, sfrag[kk], sa2, 0, 0, 0);
    }
    float cst = wsf[384];
    if (hi == 0) a_lds[32 * w + ml] = sa2[1] + cst;  // a[j]+cst (row1 at r=1,hi=0)
    c_own = __shfl(sa2[0], ml);                      // c[j]   (row0 at r=0,hi=0)
  }
  __syncthreads();  // #2: G dead

  // ---- Sr half0 rows from waves 0-3 ----
  if (w < 4) {
    #pragma unroll
    for (int kk = 0; kk < 8; ++kk)
      *reinterpret_cast<bf16x8*>(SA + swzQ(32 * w + ml, 16 * kk + 8 * hi)) = sfrag[kk];
  }
  __syncthreads();  // #3: Sr half0 + ST half0 + a_lds ready

  // ---- attention, two passes over kappa halves ----
  const float SC = 0.088388347648318447f;  // 1/sqrt(128)
  f32x16 uacc[4];
  #pragma unroll
  for (int m = 0; m < 4; ++m) uacc[m] = fzero();
  float rs = 0.f;

  #pragma unroll
  for (int half = 0; half < 2; ++half) {
    #pragma unroll
    for (int c4 = 0; c4 < 4; ++c4) {
      int kt = 4 * half + c4;
      f32x16 sa = fzero();
      __builtin_amdgcn_s_setprio(1);
      #pragma unroll
      for (int kk = 0; kk < 8; ++kk) {
        bf16x8 sr = *reinterpret_cast<const bf16x8*>(
            SA + swzQ(32 * c4 + ml, 16 * kk + 8 * hi));
        sa = __builtin_amdgcn_mfma_f32_32x32x16_bf16(sr, rfrag[kk], sa, 0, 0, 0);
      }
      __builtin_amdgcn_s_setprio(0);
      float p[16];
      #pragma unroll
      for (int r = 0; r < 16; ++r) {
        float av = a_lds[32 * kt + rowmap(r, hi)];
        p[r] = fmaxf((sa[r] + av + c_own) * SC, 0.f);
        rs += p[r];
      }
      bf16x8 pf0 = mk_frag(p[0], p[1], p[2], p[3], p[4], p[5], p[6], p[7], lane);
      bf16x8 pf1 = mk_frag(p[8], p[9], p[10], p[11], p[12], p[13], p[14], p[15], lane);
      __builtin_amdgcn_s_setprio(1);
      #pragma unroll
      for (int m = 0; m < 4; ++m) {
        bf16x8 st0 = *reinterpret_cast<const bf16x8*>(
            SB + swzQ(32 * m + ml, 32 * c4 + 8 * hi));
        uacc[m] = __builtin_amdgcn_mfma_f32_32x32x16_bf16(st0, pf0, uacc[m], 0, 0, 0);
        bf16x8 st1 = *reinterpret_cast<const bf16x8*>(
            SB + swzQ(32 * m + ml, 32 * c4 + 16 + 8 * hi));
        uacc[m] = __builtin_amdgcn_mfma_f32_32x32x16_bf16(st1, pf1, uacc[m], 0, 0, 0);
      }
      __builtin_amdgcn_s_setprio(0);
    }
    if (half == 0) {
      __syncthreads();  // #4: all half0 reads done
      if (w >= 4) {     // refill both layouts with kappa 128..255 (raw reload)
        bf16x8 tf[8];
        const float* srow = S + sbase + (size_t)(32 * w + ml) * 128;
        #pragma unroll
        for (int kk = 0; kk < 8; ++kk) {
          float4 a = *reinterpret_cast<const float4*>(srow + 16 * kk + 8 * hi);
          float4 b = *reinterpret_cast<const float4*>(srow + 16 * kk + 8 * hi + 4);
          bf16x8 f;
          f[0] = (__bf16)a.x; f[1] = (__bf16)a.y; f[2] = (__bf16)a.z; f[3] = (__bf16)a.w;
          f[4] = (__bf16)b.x; f[5] = (__bf16)b.y; f[6] = (__bf16)b.z; f[7] = (__bf16)b.w;
          tf[kk] = f;
        }
        st_write(SB, 32 * (w - 4), tf, ml, hi);
        #pragma unroll
        for (int kk = 0; kk < 8; ++kk)
          *reinterpret_cast<bf16x8*>(
              SA + swzQ(32 * (w - 4) + ml, 16 * kk + 8 * hi)) = tf[kk];
      }
      __syncthreads();  // #5: half1 tiles ready
    }
  }

  // ---- rowsum(P) exchange; H^T DMA; U -> A-frags; residual prefetch ----
  {
    float rs2 = rs + __shfl_xor(rs, 32);
    if (hi == 0) rs_lds[32 * w + ml] = rs2;
  }
  __syncthreads();  // #6: SA/SB dead
  #pragma unroll
  for (int j = 0; j < 4; ++j) {
    int c = w + 8 * j;
    gld16(ws + 32768 + c * 1024 + lane * 16, SA + c * 1024);
  }
  bf16x8 cf[8];
  #pragma unroll
  for (int m = 0; m < 4; ++m) {
    cf[2 * m]     = mk_frag(uacc[m][0], uacc[m][1], uacc[m][2], uacc[m][3],
                            uacc[m][4], uacc[m][5], uacc[m][6], uacc[m][7], lane);
    cf[2 * m + 1] = mk_frag(uacc[m][8], uacc[m][9], uacc[m][10], uacc[m][11],
                            uacc[m][12], uacc[m][13], uacc[m][14], uacc[m][15], lane);
  }
  float resv[4][16];
  #pragma unroll
  for (int t = 0; t < 4; ++t) {
    #pragma unroll
    for (int r = 0; r < 16; ++r)
      resv[t][r] = S[sbase + (size_t)(32 * w + rowmap(r, hi)) * 128 + 32 * t + ml];
  }
  __syncthreads();  // #7: H^T staged; rs_lds visible

  // ---- out = U.H (+ rs*w2 + bo + residual, LN) ----
  f32x16 oa[4];
  #pragma unroll
  for (int t = 0; t < 4; ++t) oa[t] = fzero();
  #pragma unroll
  for (int kk = 0; kk < 8; ++kk) {
    #pragma unroll
    for (int t = 0; t < 4; ++t) {
      bf16x8 hf = *reinterpret_cast<const bf16x8*>(
          SA + swzQ(32 * t + ml, 16 * kk + 8 * hi));
      oa[t] = __builtin_amdgcn_mfma_f32_32x32x16_bf16(cf[kk], hf, oa[t], 0, 0, 0);
    }
  }

  float gg[4], lbv[4], bov[4], w2v[4];
  #pragma unroll
  for (int t = 0; t < 4; ++t) {
    gg[t]  = lg[32 * t + ml];
    lbv[t] = lb[32 * t + ml];
    bov[t] = bo[32 * t + ml];
    w2v[t] = wsf[256 + 32 * t + ml];
  }
  float rsr[16];
  #pragma unroll
  for (int r = 0; r < 16; ++r) rsr[r] = rs_lds[32 * w + rowmap(r, hi)];

  float sum[16], ssq[16];
  #pragma unroll
  for (int r = 0; r < 16; ++r) { sum[r] = 0.f; ssq[r] = 0.f; }
  #pragma unroll
  for (int t = 0; t < 4; ++t) {
    #pragma unroll
    for (int r = 0; r < 16; ++r) {
      float x = oa[t][r] + rsr[r] * w2v[t] + bov[t] + resv[t][r];
      oa[t][r] = x;
      sum[r] += x;
      ssq[r] += x * x;
    }
  }
  #pragma unroll
  for (int r = 0; r < 16; ++r) {
    float s_ = sum[r], q_ = ssq[r];
    #pragma unroll
    for (int m = 1; m <= 16; m <<= 1) {
      s_ += __shfl_xor(s_, m);
      q_ += __shfl_xor(q_, m);
    }
    float mu = s_ * (1.f / 128.f);
    float var = q_ * (1.f / 128.f) - mu * mu;
    float rq = rsqrtf(var + 1e-5f);
    float* orow = out + sbase + (size_t)(32 * w + rowmap(r, hi)) * 128;
    #pragma unroll
    for (int t = 0; t < 4; ++t)
      orow[32 * t + ml] = (oa[t][r] - mu) * rq * gg[t] + lbv[t];
  }
}

extern "C" void kernel_launch(void* const* d_in, const int* in_sizes, int n_in,
                              void* d_out, int out_size, void* d_ws, size_t ws_size,
                              hipStream_t stream) {
  (void)in_sizes; (void)n_in; (void)out_size; (void)ws_size;
  const float* S  = (const float*)d_in[1];
  const float* Wq = (const float*)d_in[2];
  const float* bq = (const float*)d_in[3];
  const float* Wk = (const float*)d_in[4];
  const float* bk = (const float*)d_in[5];
  const float* Wv = (const float*)d_in[6];
  const float* bv = (const float*)d_in[7];
  const float* Wo = (const float*)d_in[8];
  const float* bo = (const float*)d_in[9];
  const float* lg = (const float*)d_in[10];
  const float* lb = (const float*)d_in[11];
  float* out = (float*)d_out;
  char* ws = (char*)d_ws;

  // ws layout: [G bf16-swz 32K][H^T bf16-swz 32K][v1,v2,w2 f32 3*512B][cst f32]
  constexpr int PSM = (128 * 129 + 16 * 129) * 4;  // 74304
  (void)hipFuncSetAttribute(reinterpret_cast<const void*>(&prep_mat),
                            hipFuncAttributeMaxDynamicSharedMemorySize, PSM);
  prep_mat<<<dim3(8), dim3(256), PSM, stream>>>(Wq, Wk, ws, 0);
  prep_mat<<<dim3(8), dim3(256), PSM, stream>>>(Wo, Wv, ws + 32768, 1);
  prep_v<<<dim3(1), dim3(128), 0, stream>>>(Wq, Wk, Wo, bq, bk, bv,
                                            (float*)(ws + 65536));

  constexpr int SMEM = 67584;  // 32K + 32K + 2K -> 2 blocks/CU (LDS 135K/160K)
  (void)hipFuncSetAttribute(reinterpret_cast<const void*>(&sapd_fused),
                            hipFuncAttributeMaxDynamicSharedMemorySize, SMEM);
  sapd_fused<<<dim3(512), dim3(512), SMEM, stream>>>(S, bo, lg, lb, ws, out);
}

// Round 9
// 92.072 us; speedup vs baseline: 2.5382x; 2.5382x over previous
//
#include <hip/hip_runtime.h>

#define DEV static __device__ __forceinline__

typedef __bf16 bf16x8 __attribute__((ext_vector_type(8)));
typedef float  f32x16 __attribute__((ext_vector_type(16)));

// 32x32 MFMA C/D row for reg r, lane-half hi (verified m74/m101)
DEV int rowmap(int r, int hi) { return (r & 3) + 8 * (r >> 2) + 4 * hi; }

// 256B-row bf16 tiles: 16B-block XOR4 swizzle (full bank spread)
DEV int swzQ(int row, int col) {
  return row * 256 + (((((col >> 3) ^ (row & 15)) << 3) | (col & 7)) << 1);
}

DEV unsigned pack2(float lo, float hi) {
  union { __bf16 h[2]; unsigned u; } x;
  x.h[0] = (__bf16)lo; x.h[1] = (__bf16)hi;
  return x.u;
}

// D-layout 16-row slab -> A/B fragment; half-swap via shfl_xor(.,32)+select.
DEV bf16x8 mk_frag(float d0, float d1, float d2, float d3,
                   float d4, float d5, float d6, float d7, int lane) {
  unsigned a0 = pack2(d0, d1), a1 = pack2(d2, d3);
  unsigned b0 = pack2(d4, d5), b1 = pack2(d6, d7);
  unsigned a0s = __shfl_xor(a0, 32), a1s = __shfl_xor(a1, 32);
  unsigned b0s = __shfl_xor(b0, 32), b1s = __shfl_xor(b1, 32);
  bool lo = lane < 32;
  union { unsigned u[4]; bf16x8 v; } r;
  r.u[0] = lo ? a0  : b0s;
  r.u[1] = lo ? a1  : b1s;
  r.u[2] = lo ? a0s : b0;
  r.u[3] = lo ? a1s : b1;
  return r.v;
}

DEV f32x16 fzero() {
  f32x16 z;
  #pragma unroll
  for (int i = 0; i < 16; ++i) z[i] = 0.f;
  return z;
}

// async global->LDS, 16B/lane, wave-uniform LDS base (m97 pattern)
DEV void gld16(const char* g, char* l) {
  __builtin_amdgcn_global_load_lds(
      (const __attribute__((address_space(1))) void*)g,
      (__attribute__((address_space(3))) void*)l, 16, 0, 0);
}

// Write S^T half-tile [128 e][128 kloc] from row-fragments.
DEV void st_write(char* SB, int colbase, const bf16x8 sf[8], int ml, int hi) {
  #pragma unroll
  for (int kk = 0; kk < 8; ++kk) {
    union { bf16x8 v; unsigned u[4]; } o, q;
    o.v = sf[kk];
    #pragma unroll
    for (int x = 0; x < 4; ++x) q.u[x] = __shfl_xor(o.u[x], 1);
    bool even = ((ml & 1) == 0);
    if (even ? (kk < 4) : (kk >= 4)) {
      int col = colbase + (ml & ~1);
      #pragma unroll
      for (int i = 0; i < 8; ++i) {
        int e = 16 * kk + 8 * hi + i;
        union { __bf16 h[2]; unsigned u; } pk;
        pk.h[0] = even ? o.v[i] : q.v[i];
        pk.h[1] = even ? q.v[i] : o.v[i];
        *reinterpret_cast<unsigned*>(SB + swzQ(e, col)) = pk.u;
      }
    }
  }
}

// prep: G[a,b] = sum_d Wq[a,d] Wk[b,d]   (blocks 0..127,  -> dst+0)
//       H^T[a,b] = sum_d Wv[b,d] Wo[d,a] (blocks 128..255, -> dst+32K)
// one block per output row a, one thread per column b.
__global__ __launch_bounds__(128)
void prep_gh(const float* __restrict__ Wq, const float* __restrict__ Wk,
             const float* __restrict__ Wv, const float* __restrict__ Wo,
             char* __restrict__ dst) {
  __shared__ float xl[128];
  const int a = blockIdx.x & 127;
  const int mode = blockIdx.x >> 7;   // 0=G, 1=H^T
  const int b = threadIdx.x;
  xl[b] = (mode == 0) ? Wq[a * 128 + b] : Wo[b * 128 + a];
  __syncthreads();
  const float* yrow = ((mode == 0) ? Wk : Wv) + b * 128;
  float4 ac = {0.f, 0.f, 0.f, 0.f};
  #pragma unroll
  for (int d = 0; d < 128; d += 4) {
    float4 y = *reinterpret_cast<const float4*>(yrow + d);
    float4 x = *reinterpret_cast<const float4*>(xl + d);
    ac.x += x.x * y.x; ac.y += x.y * y.y;
    ac.z += x.z * y.z; ac.w += x.w * y.w;
  }
  float acc = (ac.x + ac.y) + (ac.z + ac.w);
  *reinterpret_cast<__bf16*>(dst + mode * 32768 + swzQ(a, b)) = (__bf16)acc;
}

// prep: v1[e]=Wq[e,:].bk, v2[e]=Wk[e,:].bq, w2[e]=bv.Wo[:,e], cst=bq.bk
// 4 blocks x 128 threads, one job per block.
__global__ __launch_bounds__(128)
void prep_v(const float* __restrict__ Wq, const float* __restrict__ Wk,
            const float* __restrict__ Wo,
            const float* __restrict__ bq, const float* __restrict__ bk,
            const float* __restrict__ bv, float* __restrict__ dstf) {
  const int e = threadIdx.x;
  const int m = blockIdx.x;
  if (m == 0 || m == 1) {
    const float* Wrow = (m == 0 ? Wq : Wk) + e * 128;
    const float* bb = (m == 0) ? bk : bq;
    float4 ac = {0.f, 0.f, 0.f, 0.f};
    #pragma unroll
    for (int d = 0; d < 128; d += 4) {
      float4 wv = *reinterpret_cast<const float4*>(Wrow + d);
      float4 bv4 = *reinterpret_cast<const float4*>(bb + d);
      ac.x += wv.x * bv4.x; ac.y += wv.y * bv4.y;
      ac.z += wv.z * bv4.z; ac.w += wv.w * bv4.w;
    }
    dstf[m * 128 + e] = (ac.x + ac.y) + (ac.z + ac.w);
  } else if (m == 2) {
    float a3 = 0.f, a3b = 0.f;
    #pragma unroll
    for (int d = 0; d < 128; d += 2) {   // coalesced across threads at each d
      a3  += bv[d] * Wo[d * 128 + e];
      a3b += bv[d + 1] * Wo[(d + 1) * 128 + e];
    }
    dstf[256 + e] = a3 + a3b;
  } else {
    __shared__ float part[128];
    part[e] = bq[e] * bk[e];
    __syncthreads();
    if (e == 0) {
      float c = 0.f;
      #pragma unroll
      for (int i = 0; i < 128; ++i) c += part[i];
      dstf[384] = c;
    }
  }
}

// Main: scores = S G S^T + a + c + cst (relu, scale), U = P S, out = U H + rs w2 + bo.
// LDS: SA 32K (G -> Sr-half -> H^T), SB 32K (S^T-half), spare 2K (a[256], rs[256]).
// 66K LDS -> 2 blocks/CU, 16 waves/CU = 4/SIMD; 512-thr blocks -> VGPR ~128 (proven).
__global__ __launch_bounds__(512, 2)
void sapd_fused(const float* __restrict__ S,
                const float* __restrict__ bo,
                const float* __restrict__ lg, const float* __restrict__ lb,
                const char* __restrict__ ws,
                float* __restrict__ out)
{
  extern __shared__ char smem[];
  char* SA = smem;
  char* SB = smem + 32768;
  float* a_lds  = reinterpret_cast<float*>(smem + 65536);  // [256]
  float* rs_lds = a_lds + 256;                             // [256]

  const int tid  = threadIdx.x;
  const int lane = tid & 63;
  const int w    = tid >> 6;    // wave 0..7 owns j rows [32w, 32w+32)
  const int ml   = lane & 31;
  const int hi   = lane >> 5;
  const size_t sbase = (size_t)blockIdx.x * (256 * 128);
  const float* wsf = reinterpret_cast<const float*>(ws + 65536);

  // ---- DMA G -> SA (32 x 1KB chunks) ----
  #pragma unroll
  for (int j = 0; j < 4; ++j) {
    int c = w + 8 * j;
    gld16(ws + c * 1024 + lane * 16, SA + c * 1024);
  }

  // ---- S row-fragments (own 32 rows) ----
  bf16x8 sfrag[8];
  {
    const float* srow = S + sbase + (size_t)(32 * w + ml) * 128;
    #pragma unroll
    for (int kk = 0; kk < 8; ++kk) {
      float4 a = *reinterpret_cast<const float4*>(srow + 16 * kk + 8 * hi);
      float4 b = *reinterpret_cast<const float4*>(srow + 16 * kk + 8 * hi + 4);
      bf16x8 f;
      f[0] = (__bf16)a.x; f[1] = (__bf16)a.y; f[2] = (__bf16)a.z; f[3] = (__bf16)a.w;
      f[4] = (__bf16)b.x; f[5] = (__bf16)b.y; f[6] = (__bf16)b.z; f[7] = (__bf16)b.w;
      sfrag[kk] = f;
    }
  }

  // ---- S^T half0 (kappa 0..127) from waves 0-3 ----
  if (w < 4) st_write(SB, 32 * w, sfrag, ml, hi);
  __syncthreads();  // #1: G staged

  // ---- R-proj SWAPPED: racc[e][j] = sum_e' G[e,e'] S[j,e'] -> rfrag regs ----
  bf16x8 rfrag[8];
  {
    f32x16 racc[4];
    #pragma unroll
    for (int t = 0; t < 4; ++t) racc[t] = fzero();
    #pragma unroll
    for (int kk = 0; kk < 8; ++kk) {
      #pragma unroll
      for (int t = 0; t < 4; ++t) {
        bf16x8 gf = *reinterpret_cast<const bf16x8*>(
            SA + swzQ(32 * t + ml, 16 * kk + 8 * hi));
        racc[t] = __builtin_amdgcn_mfma_f32_32x32x16_bf16(gf, sfrag[kk], racc[t], 0, 0, 0);
      }
    }
    #pragma unroll
    for (int t = 0; t < 4; ++t) {
      rfrag[2 * t]     = mk_frag(racc[t][0], racc[t][1], racc[t][2], racc[t][3],
                                 racc[t][4], racc[t][5], racc[t][6], racc[t][7], lane);
      rfrag[2 * t + 1] = mk_frag(racc[t][8], racc[t][9], racc[t][10], racc[t][11],
                                 racc[t][12], racc[t][13], racc[t][14], racc[t][15], lane);
    }
  }

  // ---- bias MFMA: row0 = c[j] = S.v2, row1 = a[j] = S.v1 ----
  float c_own;
  {
    f32x16 sa2 = fzero();
    #pragma unroll
    for (int kk = 0; kk < 8; ++kk) {
      bf16x8 vmf;
      if (ml < 2) {
        const float* vp = wsf + (ml == 0 ? 128 : 0);  // row0=v2(c), row1=v1(a)
        #pragma unroll
        for (int i = 0; i < 8; ++i) vmf[i] = (__bf16)vp[16 * kk + 8 * hi + i];
      } else {
        #pragma unroll
        for (int i = 0; i < 8; ++i) vmf[i] = (__bf16)0.f;
      }
      sa2 = __builtin_amdgcn_mfma_f32_32x32x16_bf16(vmf, sfrag[kk], sa2, 0, 0, 0);
    }
    float cst = wsf[384];
    if (hi == 0) a_lds[32 * w + ml] = sa2[1] + cst;  // a[j]+cst (row1 at r=1,hi=0)
    c_own = __shfl(sa2[0], ml);                      // c[j]   (row0 at r=0,hi=0)
  }
  __syncthreads();  // #2: G dead

  // ---- Sr half0 rows from waves 0-3 ----
  if (w < 4) {
    #pragma unroll
    for (int kk = 0; kk < 8; ++kk)
      *reinterpret_cast<bf16x8*>(SA + swzQ(32 * w + ml, 16 * kk + 8 * hi)) = sfrag[kk];
  }
  __syncthreads();  // #3: Sr half0 + ST half0 + a_lds ready

  // ---- attention, two passes over kappa halves ----
  const float SC = 0.088388347648318447f;  // 1/sqrt(128)
  f32x16 uacc[4];
  #pragma unroll
  for (int m = 0; m < 4; ++m) uacc[m] = fzero();
  float rs = 0.f;

  #pragma unroll
  for (int half = 0; half < 2; ++half) {
    #pragma unroll
    for (int c4 = 0; c4 < 4; ++c4) {
      int kt = 4 * half + c4;
      f32x16 sa = fzero();
      __builtin_amdgcn_s_setprio(1);
      #pragma unroll
      for (int kk = 0; kk < 8; ++kk) {
        bf16x8 sr = *reinterpret_cast<const bf16x8*>(
            SA + swzQ(32 * c4 + ml, 16 * kk + 8 * hi));
        sa = __builtin_amdgcn_mfma_f32_32x32x16_bf16(sr, rfrag[kk], sa, 0, 0, 0);
      }
      __builtin_amdgcn_s_setprio(0);
      float p[16];
      #pragma unroll
      for (int r = 0; r < 16; ++r) {
        float av = a_lds[32 * kt + rowmap(r, hi)];
        p[r] = fmaxf((sa[r] + av + c_own) * SC, 0.f);
        rs += p[r];
      }
      bf16x8 pf0 = mk_frag(p[0], p[1], p[2], p[3], p[4], p[5], p[6], p[7], lane);
      bf16x8 pf1 = mk_frag(p[8], p[9], p[10], p[11], p[12], p[13], p[14], p[15], lane);
      __builtin_amdgcn_s_setprio(1);
      #pragma unroll
      for (int m = 0; m < 4; ++m) {
        bf16x8 st0 = *reinterpret_cast<const bf16x8*>(
            SB + swzQ(32 * m + ml, 32 * c4 + 8 * hi));
        uacc[m] = __builtin_amdgcn_mfma_f32_32x32x16_bf16(st0, pf0, uacc[m], 0, 0, 0);
        bf16x8 st1 = *reinterpret_cast<const bf16x8*>(
            SB + swzQ(32 * m + ml, 32 * c4 + 16 + 8 * hi));
        uacc[m] = __builtin_amdgcn_mfma_f32_32x32x16_bf16(st1, pf1, uacc[m], 0, 0, 0);
      }
      __builtin_amdgcn_s_setprio(0);
    }
    if (half == 0) {
      __syncthreads();  // #4: all half0 reads done
      if (w >= 4) {     // refill both layouts with kappa 128..255 (raw reload)
        bf16x8 tf[8];
        const float* srow = S + sbase + (size_t)(32 * w + ml) * 128;
        #pragma unroll
        for (int kk = 0; kk < 8; ++kk) {
          float4 a = *reinterpret_cast<const float4*>(srow + 16 * kk + 8 * hi);
          float4 b = *reinterpret_cast<const float4*>(srow + 16 * kk + 8 * hi + 4);
          bf16x8 f;
          f[0] = (__bf16)a.x; f[1] = (__bf16)a.y; f[2] = (__bf16)a.z; f[3] = (__bf16)a.w;
          f[4] = (__bf16)b.x; f[5] = (__bf16)b.y; f[6] = (__bf16)b.z; f[7] = (__bf16)b.w;
          tf[kk] = f;
        }
        st_write(SB, 32 * (w - 4), tf, ml, hi);
        #pragma unroll
        for (int kk = 0; kk < 8; ++kk)
          *reinterpret_cast<bf16x8*>(
              SA + swzQ(32 * (w - 4) + ml, 16 * kk + 8 * hi)) = tf[kk];
      }
      __syncthreads();  // #5: half1 tiles ready
    }
  }

  // ---- rowsum(P) exchange; H^T DMA; U -> A-frags; residual prefetch ----
  {
    float rs2 = rs + __shfl_xor(rs, 32);
    if (hi == 0) rs_lds[32 * w + ml] = rs2;
  }
  __syncthreads();  // #6: SA/SB dead
  #pragma unroll
  for (int j = 0; j < 4; ++j) {
    int c = w + 8 * j;
    gld16(ws + 32768 + c * 1024 + lane * 16, SA + c * 1024);
  }
  bf16x8 cf[8];
  #pragma unroll
  for (int m = 0; m < 4; ++m) {
    cf[2 * m]     = mk_frag(uacc[m][0], uacc[m][1], uacc[m][2], uacc[m][3],
                            uacc[m][4], uacc[m][5], uacc[m][6], uacc[m][7], lane);
    cf[2 * m + 1] = mk_frag(uacc[m][8], uacc[m][9], uacc[m][10], uacc[m][11],
                            uacc[m][12], uacc[m][13], uacc[m][14], uacc[m][15], lane);
  }
  float resv[4][16];
  #pragma unroll
  for (int t = 0; t < 4; ++t) {
    #pragma unroll
    for (int r = 0; r < 16; ++r)
      resv[t][r] = S[sbase + (size_t)(32 * w + rowmap(r, hi)) * 128 + 32 * t + ml];
  }
  __syncthreads();  // #7: H^T staged; rs_lds visible

  // ---- out = U.H (+ rs*w2 + bo + residual, LN) ----
  f32x16 oa[4];
  #pragma unroll
  for (int t = 0; t < 4; ++t) oa[t] = fzero();
  #pragma unroll
  for (int kk = 0; kk < 8; ++kk) {
    #pragma unroll
    for (int t = 0; t < 4; ++t) {
      bf16x8 hf = *reinterpret_cast<const bf16x8*>(
          SA + swzQ(32 * t + ml, 16 * kk + 8 * hi));
      oa[t] = __builtin_amdgcn_mfma_f32_32x32x16_bf16(cf[kk], hf, oa[t], 0, 0, 0);
    }
  }

  float gg[4], lbv[4], bov[4], w2v[4];
  #pragma unroll
  for (int t = 0; t < 4; ++t) {
    gg[t]  = lg[32 * t + ml];
    lbv[t] = lb[32 * t + ml];
    bov[t] = bo[32 * t + ml];
    w2v[t] = wsf[256 + 32 * t + ml];
  }
  float rsr[16];
  #pragma unroll
  for (int r = 0; r < 16; ++r) rsr[r] = rs_lds[32 * w + rowmap(r, hi)];

  float sum[16], ssq[16];
  #pragma unroll
  for (int r = 0; r < 16; ++r) { sum[r] = 0.f; ssq[r] = 0.f; }
  #pragma unroll
  for (int t = 0; t < 4; ++t) {
    #pragma unroll
    for (int r = 0; r < 16; ++r) {
      float x = oa[t][r] + rsr[r] * w2v[t] + bov[t] + resv[t][r];
      oa[t][r] = x;
      sum[r] += x;
      ssq[r] += x * x;
    }
  }
  #pragma unroll
  for (int r = 0; r < 16; ++r) {
    float s_ = sum[r], q_ = ssq[r];
    #pragma unroll
    for (int m = 1; m <= 16; m <<= 1) {
      s_ += __shfl_xor(s_, m);
      q_ += __shfl_xor(q_, m);
    }
    float mu = s_ * (1.f / 128.f);
    float var = q_ * (1.f / 128.f) - mu * mu;
    float rq = rsqrtf(var + 1e-5f);
    float* orow = out + sbase + (size_t)(32 * w + rowmap(r, hi)) * 128;
    #pragma unroll
    for (int t = 0; t < 4; ++t)
      orow[32 * t + ml] = (oa[t][r] - mu) * rq * gg[t] + lbv[t];
  }
}

extern "C" void kernel_launch(void* const* d_in, const int* in_sizes, int n_in,
                              void* d_out, int out_size, void* d_ws, size_t ws_size,
                              hipStream_t stream) {
  (void)in_sizes; (void)n_in; (void)out_size; (void)ws_size;
  const float* S  = (const float*)d_in[1];
  const float* Wq = (const float*)d_in[2];
  const float* bq = (const float*)d_in[3];
  const float* Wk = (const float*)d_in[4];
  const float* bk = (const float*)d_in[5];
  const float* Wv = (const float*)d_in[6];
  const float* bv = (const float*)d_in[7];
  const float* Wo = (const float*)d_in[8];
  const float* bo = (const float*)d_in[9];
  const float* lg = (const float*)d_in[10];
  const float* lb = (const float*)d_in[11];
  float* out = (float*)d_out;
  char* ws = (char*)d_ws;

  // ws layout: [G bf16-swz 32K][H^T bf16-swz 32K][v1,v2,w2 f32 3*512B][cst f32]
  prep_gh<<<dim3(256), dim3(128), 0, stream>>>(Wq, Wk, Wv, Wo, ws);
  prep_v<<<dim3(4), dim3(128), 0, stream>>>(Wq, Wk, Wo, bq, bk, bv,
                                            (float*)(ws + 65536));

  constexpr int SMEM = 67584;  // 32K + 32K + 2K -> 2 blocks/CU (LDS 135K/160K)
  (void)hipFuncSetAttribute(reinterpret_cast<const void*>(&sapd_fused),
                            hipFuncAttributeMaxDynamicSharedMemorySize, SMEM);
  sapd_fused<<<dim3(512), dim3(512), SMEM, stream>>>(S, bo, lg, lb, ws, out);
}

// Round 10
// 87.259 us; speedup vs baseline: 2.6782x; 1.0552x over previous
//
#include <hip/hip_runtime.h>

#define DEV static __device__ __forceinline__

typedef __bf16 bf16x8 __attribute__((ext_vector_type(8)));
typedef float  f32x16 __attribute__((ext_vector_type(16)));

// 32x32 MFMA C/D row for reg r, lane-half hi (verified m74/m101)
DEV int rowmap(int r, int hi) { return (r & 3) + 8 * (r >> 2) + 4 * hi; }

// 256B-row bf16 tiles: 16B-block XOR4 swizzle (full bank spread)
DEV int swzQ(int row, int col) {
  return row * 256 + (((((col >> 3) ^ (row & 15)) << 3) | (col & 7)) << 1);
}

DEV unsigned pack2(float lo, float hi) {
  union { __bf16 h[2]; unsigned u; } x;
  x.h[0] = (__bf16)lo; x.h[1] = (__bf16)hi;
  return x.u;
}

// D-layout 16-row slab -> A/B fragment; half-swap via shfl_xor(.,32)+select.
DEV bf16x8 mk_frag(float d0, float d1, float d2, float d3,
                   float d4, float d5, float d6, float d7, int lane) {
  unsigned a0 = pack2(d0, d1), a1 = pack2(d2, d3);
  unsigned b0 = pack2(d4, d5), b1 = pack2(d6, d7);
  unsigned a0s = __shfl_xor(a0, 32), a1s = __shfl_xor(a1, 32);
  unsigned b0s = __shfl_xor(b0, 32), b1s = __shfl_xor(b1, 32);
  bool lo = lane < 32;
  union { unsigned u[4]; bf16x8 v; } r;
  r.u[0] = lo ? a0  : b0s;
  r.u[1] = lo ? a1  : b1s;
  r.u[2] = lo ? a0s : b0;
  r.u[3] = lo ? a1s : b1;
  return r.v;
}

DEV f32x16 fzero() {
  f32x16 z;
  #pragma unroll
  for (int i = 0; i < 16; ++i) z[i] = 0.f;
  return z;
}

// async global->LDS, 16B/lane, wave-uniform LDS base (m97 pattern)
DEV void gld16(const char* g, char* l) {
  __builtin_amdgcn_global_load_lds(
      (const __attribute__((address_space(1))) void*)g,
      (__attribute__((address_space(3))) void*)l, 16, 0, 0);
}

// Write S^T half-tile [128 e][128 kloc] from row-fragments.
DEV void st_write(char* SB, int colbase, const bf16x8 sf[8], int ml, int hi) {
  #pragma unroll
  for (int kk = 0; kk < 8; ++kk) {
    union { bf16x8 v; unsigned u[4]; } o, q;
    o.v = sf[kk];
    #pragma unroll
    for (int x = 0; x < 4; ++x) q.u[x] = __shfl_xor(o.u[x], 1);
    bool even = ((ml & 1) == 0);
    if (even ? (kk < 4) : (kk >= 4)) {
      int col = colbase + (ml & ~1);
      #pragma unroll
      for (int i = 0; i < 8; ++i) {
        int e = 16 * kk + 8 * hi + i;
        union { __bf16 h[2]; unsigned u; } pk;
        pk.h[0] = even ? o.v[i] : q.v[i];
        pk.h[1] = even ? q.v[i] : o.v[i];
        *reinterpret_cast<unsigned*>(SB + swzQ(e, col)) = pk.u;
      }
    }
  }
}

// prep: G[a,b] = sum_d Wq[a,d] Wk[b,d]   (blocks 0..127,  -> dst+0)
//       H^T[a,b] = sum_d Wv[b,d] Wo[d,a] (blocks 128..255, -> dst+32K)
__global__ __launch_bounds__(128)
void prep_gh(const float* __restrict__ Wq, const float* __restrict__ Wk,
             const float* __restrict__ Wv, const float* __restrict__ Wo,
             char* __restrict__ dst) {
  __shared__ float xl[128];
  const int a = blockIdx.x & 127;
  const int mode = blockIdx.x >> 7;   // 0=G, 1=H^T
  const int b = threadIdx.x;
  xl[b] = (mode == 0) ? Wq[a * 128 + b] : Wo[b * 128 + a];
  __syncthreads();
  const float* yrow = ((mode == 0) ? Wk : Wv) + b * 128;
  float4 ac = {0.f, 0.f, 0.f, 0.f};
  #pragma unroll
  for (int d = 0; d < 128; d += 4) {
    float4 y = *reinterpret_cast<const float4*>(yrow + d);
    float4 x = *reinterpret_cast<const float4*>(xl + d);
    ac.x += x.x * y.x; ac.y += x.y * y.y;
    ac.z += x.z * y.z; ac.w += x.w * y.w;
  }
  float acc = (ac.x + ac.y) + (ac.z + ac.w);
  *reinterpret_cast<__bf16*>(dst + mode * 32768 + swzQ(a, b)) = (__bf16)acc;
}

// prep: v1[e]=Wq[e,:].bk, v2[e]=Wk[e,:].bq, w2[e]=bv.Wo[:,e], cst=bq.bk
__global__ __launch_bounds__(128)
void prep_v(const float* __restrict__ Wq, const float* __restrict__ Wk,
            const float* __restrict__ Wo,
            const float* __restrict__ bq, const float* __restrict__ bk,
            const float* __restrict__ bv, float* __restrict__ dstf) {
  const int e = threadIdx.x;
  const int m = blockIdx.x;
  if (m == 0 || m == 1) {
    const float* Wrow = (m == 0 ? Wq : Wk) + e * 128;
    const float* bb = (m == 0) ? bk : bq;
    float4 ac = {0.f, 0.f, 0.f, 0.f};
    #pragma unroll
    for (int d = 0; d < 128; d += 4) {
      float4 wv = *reinterpret_cast<const float4*>(Wrow + d);
      float4 bv4 = *reinterpret_cast<const float4*>(bb + d);
      ac.x += wv.x * bv4.x; ac.y += wv.y * bv4.y;
      ac.z += wv.z * bv4.z; ac.w += wv.w * bv4.w;
    }
    dstf[m * 128 + e] = (ac.x + ac.y) + (ac.z + ac.w);
  } else if (m == 2) {
    float a3 = 0.f, a3b = 0.f;
    #pragma unroll
    for (int d = 0; d < 128; d += 2) {
      a3  += bv[d] * Wo[d * 128 + e];
      a3b += bv[d + 1] * Wo[(d + 1) * 128 + e];
    }
    dstf[256 + e] = a3 + a3b;
  } else {
    __shared__ float part[128];
    part[e] = bq[e] * bk[e];
    __syncthreads();
    if (e == 0) {
      float c = 0.f;
      #pragma unroll
      for (int i = 0; i < 128; ++i) c += part[i];
      dstf[384] = c;
    }
  }
}

// Main: scores = Sr.(G S^T + v1) + c[j] + cst (relu,scale); U = P S; out = U H + rs w2 + bo.
// LDS exactly 64K: SA 32K (G -> Sr-half -> H^T), SB 32K (S^T-half).
// a[kappa]-bias folded into rfrag (racc init = v1); rowsum exchanged via shfl.
__global__ __launch_bounds__(512, 2)
void sapd_fused(const float* __restrict__ S,
                const float* __restrict__ bo,
                const float* __restrict__ lg, const float* __restrict__ lb,
                const char* __restrict__ ws,
                float* __restrict__ out)
{
  extern __shared__ char smem[];
  char* SA = smem;
  char* SB = smem + 32768;

  const int tid  = threadIdx.x;
  const int lane = tid & 63;
  const int w    = tid >> 6;    // wave 0..7 owns j rows [32w, 32w+32)
  const int ml   = lane & 31;
  const int hi   = lane >> 5;
  const size_t sbase = (size_t)blockIdx.x * (256 * 128);
  const float* wsf = reinterpret_cast<const float*>(ws + 65536);

  // ---- DMA G -> SA (32 x 1KB chunks) ----
  #pragma unroll
  for (int j = 0; j < 4; ++j) {
    int c = w + 8 * j;
    gld16(ws + c * 1024 + lane * 16, SA + c * 1024);
  }

  // ---- S row-fragments (own 32 rows) ----
  bf16x8 sfrag[8];
  {
    const float* srow = S + sbase + (size_t)(32 * w + ml) * 128;
    #pragma unroll
    for (int kk = 0; kk < 8; ++kk) {
      float4 a = *reinterpret_cast<const float4*>(srow + 16 * kk + 8 * hi);
      float4 b = *reinterpret_cast<const float4*>(srow + 16 * kk + 8 * hi + 4);
      bf16x8 f;
      f[0] = (__bf16)a.x; f[1] = (__bf16)a.y; f[2] = (__bf16)a.z; f[3] = (__bf16)a.w;
      f[4] = (__bf16)b.x; f[5] = (__bf16)b.y; f[6] = (__bf16)b.z; f[7] = (__bf16)b.w;
      sfrag[kk] = f;
    }
  }

  // ---- S^T half0 (kappa 0..127) from waves 0-3 ----
  if (w < 4) st_write(SB, 32 * w, sfrag, ml, hi);
  __syncthreads();  // #1: G staged

  // ---- R'-proj SWAPPED: racc init = v1[e]; racc += G S^T -> rfrag regs ----
  bf16x8 rfrag[8];
  {
    f32x16 racc[4];
    #pragma unroll
    for (int t = 0; t < 4; ++t) {
      #pragma unroll
      for (int r = 0; r < 16; ++r)
        racc[t][r] = wsf[32 * t + rowmap(r, hi)];  // v1[e] (a-bias fold)
    }
    #pragma unroll
    for (int kk = 0; kk < 8; ++kk) {
      #pragma unroll
      for (int t = 0; t < 4; ++t) {
        bf16x8 gf = *reinterpret_cast<const bf16x8*>(
            SA + swzQ(32 * t + ml, 16 * kk + 8 * hi));
        racc[t] = __builtin_amdgcn_mfma_f32_32x32x16_bf16(gf, sfrag[kk], racc[t], 0, 0, 0);
      }
    }
    #pragma unroll
    for (int t = 0; t < 4; ++t) {
      rfrag[2 * t]     = mk_frag(racc[t][0], racc[t][1], racc[t][2], racc[t][3],
                                 racc[t][4], racc[t][5], racc[t][6], racc[t][7], lane);
      rfrag[2 * t + 1] = mk_frag(racc[t][8], racc[t][9], racc[t][10], racc[t][11],
                                 racc[t][12], racc[t][13], racc[t][14], racc[t][15], lane);
    }
  }

  // ---- bias MFMA row0: c[j] = S.v2 ----
  float c_own;
  {
    f32x16 sa2 = fzero();
    #pragma unroll
    for (int kk = 0; kk < 8; ++kk) {
      bf16x8 vmf;
      if (ml == 0) {
        #pragma unroll
        for (int i = 0; i < 8; ++i) vmf[i] = (__bf16)wsf[128 + 16 * kk + 8 * hi + i];
      } else {
        #pragma unroll
        for (int i = 0; i < 8; ++i) vmf[i] = (__bf16)0.f;
      }
      sa2 = __builtin_amdgcn_mfma_f32_32x32x16_bf16(vmf, sfrag[kk], sa2, 0, 0, 0);
    }
    c_own = __shfl(sa2[0], ml) + wsf[384];  // c[j=32w+ml] + cst
  }
  __syncthreads();  // #2: G dead

  // ---- Sr half0 rows from waves 0-3 ----
  if (w < 4) {
    #pragma unroll
    for (int kk = 0; kk < 8; ++kk)
      *reinterpret_cast<bf16x8*>(SA + swzQ(32 * w + ml, 16 * kk + 8 * hi)) = sfrag[kk];
  }
  __syncthreads();  // #3: Sr half0 + ST half0 ready

  // ---- attention, two passes over kappa halves ----
  const float SC = 0.088388347648318447f;  // 1/sqrt(128)
  f32x16 uacc[4];
  #pragma unroll
  for (int m = 0; m < 4; ++m) uacc[m] = fzero();
  float rs = 0.f;

  #pragma unroll
  for (int half = 0; half < 2; ++half) {
    #pragma unroll
    for (int c4 = 0; c4 < 4; ++c4) {
      f32x16 sa = fzero();
      __builtin_amdgcn_s_setprio(1);
      #pragma unroll
      for (int kk = 0; kk < 8; ++kk) {
        bf16x8 sr = *reinterpret_cast<const bf16x8*>(
            SA + swzQ(32 * c4 + ml, 16 * kk + 8 * hi));
        sa = __builtin_amdgcn_mfma_f32_32x32x16_bf16(sr, rfrag[kk], sa, 0, 0, 0);
      }
      __builtin_amdgcn_s_setprio(0);
      float p[16];
      #pragma unroll
      for (int r = 0; r < 16; ++r) {
        p[r] = fmaxf((sa[r] + c_own) * SC, 0.f);
        rs += p[r];
      }
      bf16x8 pf0 = mk_frag(p[0], p[1], p[2], p[3], p[4], p[5], p[6], p[7], lane);
      bf16x8 pf1 = mk_frag(p[8], p[9], p[10], p[11], p[12], p[13], p[14], p[15], lane);
      __builtin_amdgcn_s_setprio(1);
      #pragma unroll
      for (int m = 0; m < 4; ++m) {
        bf16x8 st0 = *reinterpret_cast<const bf16x8*>(
            SB + swzQ(32 * m + ml, 32 * c4 + 8 * hi));
        uacc[m] = __builtin_amdgcn_mfma_f32_32x32x16_bf16(st0, pf0, uacc[m], 0, 0, 0);
        bf16x8 st1 = *reinterpret_cast<const bf16x8*>(
            SB + swzQ(32 * m + ml, 32 * c4 + 16 + 8 * hi));
        uacc[m] = __builtin_amdgcn_mfma_f32_32x32x16_bf16(st1, pf1, uacc[m], 0, 0, 0);
      }
      __builtin_amdgcn_s_setprio(0);
    }
    if (half == 0) {
      __syncthreads();  // #4: all half0 reads done
      if (w >= 4) {     // refill both layouts with kappa 128..255 (raw reload)
        bf16x8 tf[8];
        const float* srow = S + sbase + (size_t)(32 * w + ml) * 128;
        #pragma unroll
        for (int kk = 0; kk < 8; ++kk) {
          float4 a = *reinterpret_cast<const float4*>(srow + 16 * kk + 8 * hi);
          float4 b = *reinterpret_cast<const float4*>(srow + 16 * kk + 8 * hi + 4);
          bf16x8 f;
          f[0] = (__bf16)a.x; f[1] = (__bf16)a.y; f[2] = (__bf16)a.z; f[3] = (__bf16)a.w;
          f[4] = (__bf16)b.x; f[5] = (__bf16)b.y; f[6] = (__bf16)b.z; f[7] = (__bf16)b.w;
          tf[kk] = f;
        }
        st_write(SB, 32 * (w - 4), tf, ml, hi);
        #pragma unroll
        for (int kk = 0; kk < 8; ++kk)
          *reinterpret_cast<bf16x8*>(
              SA + swzQ(32 * (w - 4) + ml, 16 * kk + 8 * hi)) = tf[kk];
      }
      __syncthreads();  // #5: half1 tiles ready
    }
  }

  // ---- rowsum via shfl; H^T DMA; U -> A-frags ----
  float rs2 = rs + __shfl_xor(rs, 32);  // full kappa-sum for j=32w+ml, all lanes
  __syncthreads();  // #6: SA/SB dead
  #pragma unroll
  for (int j = 0; j < 4; ++j) {
    int c = w + 8 * j;
    gld16(ws + 32768 + c * 1024 + lane * 16, SA + c * 1024);
  }
  bf16x8 cf[8];
  #pragma unroll
  for (int m = 0; m < 4; ++m) {
    cf[2 * m]     = mk_frag(uacc[m][0], uacc[m][1], uacc[m][2], uacc[m][3],
                            uacc[m][4], uacc[m][5], uacc[m][6], uacc[m][7], lane);
    cf[2 * m + 1] = mk_frag(uacc[m][8], uacc[m][9], uacc[m][10], uacc[m][11],
                            uacc[m][12], uacc[m][13], uacc[m][14], uacc[m][15], lane);
  }
  __syncthreads();  // #7: H^T staged

  // ---- out = U.H ----
  f32x16 oa[4];
  #pragma unroll
  for (int t = 0; t < 4; ++t) oa[t] = fzero();
  #pragma unroll
  for (int kk = 0; kk < 8; ++kk) {
    #pragma unroll
    for (int t = 0; t < 4; ++t) {
      bf16x8 hf = *reinterpret_cast<const bf16x8*>(
          SA + swzQ(32 * t + ml, 16 * kk + 8 * hi));
      oa[t] = __builtin_amdgcn_mfma_f32_32x32x16_bf16(cf[kk], hf, oa[t], 0, 0, 0);
    }
  }

  // ---- epilogue: +rs*w2 +bo +residual (streamed per t), LN, store ----
  float rsr[16];
  #pragma unroll
  for (int r = 0; r < 16; ++r) rsr[r] = __shfl(rs2, rowmap(r, hi));

  float sum[16], ssq[16];
  #pragma unroll
  for (int r = 0; r < 16; ++r) { sum[r] = 0.f; ssq[r] = 0.f; }
  #pragma unroll
  for (int t = 0; t < 4; ++t) {
    float w2t = wsf[256 + 32 * t + ml];
    float bot = bo[32 * t + ml];
    #pragma unroll
    for (int r = 0; r < 16; ++r) {
      float rv = S[sbase + (size_t)(32 * w + rowmap(r, hi)) * 128 + 32 * t + ml];
      float x = oa[t][r] + rsr[r] * w2t + bot + rv;
      oa[t][r] = x;
      sum[r] += x;
      ssq[r] += x * x;
    }
  }
  #pragma unroll
  for (int r = 0; r < 16; ++r) {
    float s_ = sum[r], q_ = ssq[r];
    #pragma unroll
    for (int m = 1; m <= 16; m <<= 1) {
      s_ += __shfl_xor(s_, m);
      q_ += __shfl_xor(q_, m);
    }
    float mu = s_ * (1.f / 128.f);
    float var = q_ * (1.f / 128.f) - mu * mu;
    float rq = rsqrtf(var + 1e-5f);
    float* orow = out + sbase + (size_t)(32 * w + rowmap(r, hi)) * 128;
    #pragma unroll
    for (int t = 0; t < 4; ++t)
      orow[32 * t + ml] = (oa[t][r] - mu) * rq * lg[32 * t + ml] + lb[32 * t + ml];
  }
}

extern "C" void kernel_launch(void* const* d_in, const int* in_sizes, int n_in,
                              void* d_out, int out_size, void* d_ws, size_t ws_size,
                              hipStream_t stream) {
  (void)in_sizes; (void)n_in; (void)out_size; (void)ws_size;
  const float* S  = (const float*)d_in[1];
  const float* Wq = (const float*)d_in[2];
  const float* bq = (const float*)d_in[3];
  const float* Wk = (const float*)d_in[4];
  const float* bk = (const float*)d_in[5];
  const float* Wv = (const float*)d_in[6];
  const float* bv = (const float*)d_in[7];
  const float* Wo = (const float*)d_in[8];
  const float* bo = (const float*)d_in[9];
  const float* lg = (const float*)d_in[10];
  const float* lb = (const float*)d_in[11];
  float* out = (float*)d_out;
  char* ws = (char*)d_ws;

  // ws layout: [G bf16-swz 32K][H^T bf16-swz 32K][v1,v2,w2 f32 3*512B][cst f32]
  prep_gh<<<dim3(256), dim3(128), 0, stream>>>(Wq, Wk, Wv, Wo, ws);
  prep_v<<<dim3(4), dim3(128), 0, stream>>>(Wq, Wk, Wo, bq, bk, bv,
                                            (float*)(ws + 65536));

  constexpr int SMEM = 65536;  // exactly 64K -> 2 blocks/CU (m132 precedent)
  (void)hipFuncSetAttribute(reinterpret_cast<const void*>(&sapd_fused),
                            hipFuncAttributeMaxDynamicSharedMemorySize, SMEM);
  sapd_fused<<<dim3(512), dim3(512), SMEM, stream>>>(S, bo, lg, lb, ws, out);
}